// Round 1
// baseline (530.304 us; speedup 1.0000x reference)
//
#include <hip/hip_runtime.h>

#define B_DIM 32
#define N_DIM 16384
#define D 128
#define LPAD 136              // padded LDS row stride (bf16 elems): 2-way bank aliasing only
#define SUM_CHUNKS 16         // chunks per batch for the column-sum pass

typedef __attribute__((ext_vector_type(8))) short short8;   // 8 bf16 = 4 VGPRs
typedef __attribute__((ext_vector_type(4))) float floatx4;  // MFMA accumulator

__device__ __forceinline__ short f2bf(float f) {
    // round-to-nearest-even fp32 -> bf16 bits
    unsigned u = __builtin_bit_cast(unsigned, f);
    u = (u + 0x7FFFu + ((u >> 16) & 1u)) >> 16;
    return (short)u;
}

// ---------------------------------------------------------------------------
// Kernel 1: per-chunk column sums of x.  grid = B*SUM_CHUNKS blocks x 256 thr.
// part[blk][d] = sum over this chunk's rows of x[b, n, d]
// ---------------------------------------------------------------------------
__global__ __launch_bounds__(256) void colsum_kernel(const float* __restrict__ x,
                                                     float* __restrict__ part) {
    const int CHUNK = N_DIM / SUM_CHUNKS;   // 1024 rows
    int b = blockIdx.x / SUM_CHUNKS;
    int chunk = blockIdx.x % SUM_CHUNKS;
    const float4* xp = (const float4*)(x + ((size_t)b * N_DIM + (size_t)chunk * CHUNK) * D);
    int cg = threadIdx.x & 31;   // column group: 4 consecutive floats
    int rl = threadIdx.x >> 5;   // row lane 0..7
    float4 acc = make_float4(0.f, 0.f, 0.f, 0.f);
    for (int r = rl; r < CHUNK; r += 8) {
        float4 v = xp[(size_t)r * 32 + cg];
        acc.x += v.x; acc.y += v.y; acc.z += v.z; acc.w += v.w;
    }
    __shared__ float4 red[256];
    red[threadIdx.x] = acc;
    __syncthreads();
    if (threadIdx.x < 32) {
        float4 s = red[threadIdx.x];
        #pragma unroll
        for (int i = 1; i < 8; i++) {
            float4 v = red[threadIdx.x + 32 * i];
            s.x += v.x; s.y += v.y; s.z += v.z; s.w += v.w;
        }
        float4* dst = (float4*)(part + (size_t)blockIdx.x * D);
        dst[cg] = s;
    }
}

// ---------------------------------------------------------------------------
// Kernel 2: pooled_bias[b][e] = bias[e] + sum_d xsum[b][d] * w2[d][e]
// grid = B blocks x 128 threads. Tiny.
// ---------------------------------------------------------------------------
__global__ __launch_bounds__(128) void pooled_kernel(const float* __restrict__ part,
                                                     const float* __restrict__ w2,
                                                     const float* __restrict__ bias,
                                                     float* __restrict__ pooled) {
    int b = blockIdx.x;
    int e = threadIdx.x;
    __shared__ float xs[D];
    float s = 0.f;
    #pragma unroll
    for (int c = 0; c < SUM_CHUNKS; c++)
        s += part[((size_t)b * SUM_CHUNKS + c) * D + e];
    xs[e] = s;
    __syncthreads();
    float acc = bias[e];
    #pragma unroll 8
    for (int d0 = 0; d0 < D; d0++) acc += xs[d0] * w2[d0 * D + e];
    pooled[b * D + e] = acc;
}

// ---------------------------------------------------------------------------
// Kernel 3: out[b,n,e] = (x @ w1)[b,n,e] + pooled_bias[b,e]
// bf16 MFMA 16x16x32; w1^T staged in LDS as bf16 (padded stride LPAD).
// grid = 1024 blocks x 256 thr (4 waves). Block = 512 rows of one batch.
// Wave = 128 rows as 8 tiles of 16 rows x 128 cols (8 e-tiles).
// ---------------------------------------------------------------------------
__global__ __launch_bounds__(256, 2) void gemm_kernel(const float* __restrict__ x,
                                                      const float* __restrict__ w1,
                                                      const float* __restrict__ pooled,
                                                      float* __restrict__ out) {
    __shared__ __align__(16) short w1t[D * LPAD];   // 34 KB -> 4 blocks/CU LDS cap
    for (int idx = threadIdx.x; idx < D * D; idx += 256) {
        int d0 = idx >> 7;       // k index
        int e  = idx & 127;      // output col
        w1t[e * LPAD + d0] = f2bf(w1[idx]);   // transpose: w1t[e][k]
    }
    __syncthreads();

    const int CHUNKS = 32;                   // 512 rows per block
    int b     = blockIdx.x / CHUNKS;
    int chunk = blockIdx.x % CHUNKS;
    int wave  = threadIdx.x >> 6;
    int lane  = threadIdx.x & 63;
    int m     = lane & 15;                   // A row / B col / C col
    int quad  = lane >> 4;                   // k-chunk selector / C row group

    size_t rowbase = (size_t)b * N_DIM + (size_t)chunk * 512 + (size_t)wave * 128;

    // pooled_bias for this lane's output column in each e-tile (loop-invariant)
    float pb[8];
    #pragma unroll
    for (int et = 0; et < 8; et++) pb[et] = pooled[b * D + et * 16 + m];

    for (int t = 0; t < 8; t++) {
        const float* xrow = x + (rowbase + (size_t)t * 16 + m) * D + quad * 8;
        floatx4 acc[8];
        #pragma unroll
        for (int et = 0; et < 8; et++) acc[et] = (floatx4){0.f, 0.f, 0.f, 0.f};

        #pragma unroll
        for (int ks = 0; ks < 4; ks++) {
            // A fragment: 8 consecutive k-elements of this lane's row
            float4 a0 = *(const float4*)(xrow + ks * 32);
            float4 a1 = *(const float4*)(xrow + ks * 32 + 4);
            short8 af;
            af[0] = f2bf(a0.x); af[1] = f2bf(a0.y); af[2] = f2bf(a0.z); af[3] = f2bf(a0.w);
            af[4] = f2bf(a1.x); af[5] = f2bf(a1.y); af[6] = f2bf(a1.z); af[7] = f2bf(a1.w);
            #pragma unroll
            for (int et = 0; et < 8; et++) {
                // B fragment: col = et*16+m, k = ks*32 + quad*8 + j  (contiguous b128)
                short8 bf = *(const short8*)&w1t[(et * 16 + m) * LPAD + ks * 32 + quad * 8];
                acc[et] = __builtin_amdgcn_mfma_f32_16x16x32_bf16(af, bf, acc[et], 0, 0, 0);
            }
        }

        // Epilogue: C/D layout col = lane&15, row = quad*4 + reg
        float* orow = out + (rowbase + (size_t)t * 16) * D;
        #pragma unroll
        for (int et = 0; et < 8; et++) {
            #pragma unroll
            for (int r = 0; r < 4; r++) {
                orow[(quad * 4 + r) * D + et * 16 + m] = acc[et][r] + pb[et];
            }
        }
    }
}

extern "C" void kernel_launch(void* const* d_in, const int* in_sizes, int n_in,
                              void* d_out, int out_size, void* d_ws, size_t ws_size,
                              hipStream_t stream) {
    const float* x    = (const float*)d_in[0];
    const float* w1   = (const float*)d_in[1];
    const float* w2   = (const float*)d_in[2];
    const float* bias = (const float*)d_in[3];
    float* out = (float*)d_out;

    // ws layout: [0, B*SUM_CHUNKS*D) partial column sums, then [.., +B*D) pooled_bias
    float* part   = (float*)d_ws;
    float* pooled = part + (size_t)B_DIM * SUM_CHUNKS * D;

    colsum_kernel<<<B_DIM * SUM_CHUNKS, 256, 0, stream>>>(x, part);
    pooled_kernel<<<B_DIM, 128, 0, stream>>>(part, w2, bias, pooled);
    gemm_kernel<<<B_DIM * 32, 256, 0, stream>>>(x, w1, pooled, out);
}